// Round 9
// baseline (436.585 us; speedup 1.0000x reference)
//
#include <hip/hip_runtime.h>

typedef __bf16 bf16;
typedef __bf16 bf16x8 __attribute__((ext_vector_type(8)));
typedef float  f32x4  __attribute__((ext_vector_type(4)));

#define MFMA16(a, b, c) __builtin_amdgcn_mfma_f32_16x16x32_bf16((a), (b), (c), 0, 0, 0)

// async global->LDS, 16 B per lane: lane l -> ldsbase + l*16 (wave-uniform base).
__device__ inline void gl_lds16(const bf16* g, bf16* l) {
  __builtin_amdgcn_global_load_lds(
      (const __attribute__((address_space(1))) void*)g,
      (__attribute__((address_space(3))) void*)l, 16, 0, 0);
}

__device__ inline bf16x8 cvt8(const float* __restrict__ f) {
  float4 a = *(const float4*)f;
  float4 b = *(const float4*)(f + 4);
  bf16x8 r;
  r[0] = (bf16)a.x; r[1] = (bf16)a.y; r[2] = (bf16)a.z; r[3] = (bf16)a.w;
  r[4] = (bf16)b.x; r[5] = (bf16)b.y; r[6] = (bf16)b.z; r[7] = (bf16)b.w;
  return r;
}

// ---------------------------------------------------------------------------
__global__ void cvt_f32_bf16(const float* __restrict__ src, bf16* __restrict__ dst,
                             int n8) {
  int i = blockIdx.x * 256 + threadIdx.x;
  if (i >= n8) return;
  *(bf16x8*)(dst + (size_t)i * 8) = cvt8(src + (size_t)i * 8);
}

// ---------------------------------------------------------------------------
// dst += src, float4-vectorized (split-K reduce for O-projection).
// ---------------------------------------------------------------------------
__global__ void add_f32(float* __restrict__ dst, const float* __restrict__ src,
                        int n4) {
  int i = blockIdx.x * 256 + threadIdx.x;
  if (i >= n4) return;
  float4 a = ((const float4*)dst)[i];
  float4 b = ((const float4*)src)[i];
  a.x += b.x; a.y += b.y; a.z += b.z; a.w += b.w;
  ((float4*)dst)[i] = a;
}

// ---------------------------------------------------------------------------
// 256x256 GEMM, 8 waves (2M x 4N), BK=64 — the ROUND-6-VERIFIED v9 schedule
// (byte-identical staging + dbuf + vmcnt(8) + 4 setprio'd compute phases;
// measured 100 us / MfmaUtil 20% / 0 bank conflicts on HW). The round-7/8
// deep-pipeline variant failed to bench twice (no counters, audit clean) —
// reverting to the verified schedule to bank the split-K O-proj win; the
// deep pipeline is retried later as a single-variable change.
// OUTM=0: fused QKV. N = 3072 = 2048(Q)+512(K)+512(V); W = wqb|wkb|wvb.
// OUTM=1: O-projection with split-K=2 (blockIdx.z picks K-half; f32 out to
//         P0 (=d_out) or P1; add_f32 folds). 256 blocks = full grid fill
//         (vs 128^2 O-proj: same work spread over all 256 CUs).
// LDS 128 KB -> 1 block/CU, 2 waves/SIMD.
// ---------------------------------------------------------------------------
template <int OUTM>
__global__ __launch_bounds__(512, 2) void gemm256(const bf16* __restrict__ qA,
                                                  const bf16* __restrict__ kA,
                                                  const bf16* __restrict__ vA,
                                                  const bf16* __restrict__ W,
                                                  bf16* __restrict__ Qb,
                                                  bf16* __restrict__ Kb,
                                                  bf16* __restrict__ Vb,
                                                  float* __restrict__ P0,
                                                  float* __restrict__ P1) {
  __shared__ alignas(16) bf16 As[2][32 * 512];   // 2 x 32 KB, frag-ordered
  __shared__ alignas(16) bf16 Bs[2][32 * 512];   // 2 x 32 KB

  const int tid  = threadIdx.x;
  const int wave = tid >> 6, lane = tid & 63;
  const int wm = wave >> 2, wn = wave & 3;       // 2M x 4N wave grid
  const int lr = lane & 15, quad = lane >> 4;
  const int n0 = blockIdx.x * 256, m0 = blockIdx.y * 256;
  const int NS = (OUTM == 0) ? 32 : 16;          // K-steps
  const int kbase = (OUTM == 0) ? 0 : blockIdx.z * 1024;

  int range = 0;
  const bf16* Ab;
  if (OUTM == 0) {
    range = (n0 < 2048) ? 0 : (n0 < 2560) ? 1 : 2;
    Ab = (range == 0) ? qA : (range == 1) ? kA : vA;
  } else {
    Ab = qA;
  }

  f32x4 vzero = {0.f, 0.f, 0.f, 0.f};
  f32x4 acc[8][4];
#pragma unroll
  for (int mt = 0; mt < 8; ++mt)
#pragma unroll
    for (int nt = 0; nt < 4; ++nt) acc[mt][nt] = vzero;

  // stage 64 frag-chunks (32 A + 32 B), 8 per wave.  Chunk c: row-block
  // mi=c>>1, k-slice s=c&1; lane l holds rows mi*16+(l&15),
  // cols k0+s*32+(l>>4)*8..+7  -> LDS linear at chunk*1KB + lane*16B.
#define STAGE256(bufi, kk)                                                      \
  do {                                                                          \
    _Pragma("unroll") for (int j = 0; j < 4; ++j) {                             \
      int c = wave * 4 + j;                                                     \
      int mi = c >> 1, sl = c & 1;                                              \
      gl_lds16(Ab + (size_t)(m0 + mi * 16 + lr) * 2048 + (kk) + sl * 32 + quad * 8, \
               &As[bufi][c * 512]);                                             \
      gl_lds16(W + (size_t)(n0 + mi * 16 + lr) * 2048 + (kk) + sl * 32 + quad * 8,  \
               &Bs[bufi][c * 512]);                                             \
    }                                                                           \
  } while (0)

  STAGE256(0, kbase);
  int cur = 0;
  for (int t = 0; t < NS; ++t) {
    if (t + 1 < NS) {
      STAGE256(cur ^ 1, kbase + (t + 1) * 64);
      asm volatile("s_waitcnt vmcnt(8)" ::: "memory");  // tile t complete
    } else {
      asm volatile("s_waitcnt vmcnt(0)" ::: "memory");
    }
    __builtin_amdgcn_s_barrier();

    const bf16* as = As[cur];
    const bf16* bs = Bs[cur];
    bf16x8 af[4], bf0[4], bf1[4];

    // ---- phase 0: s=0, row-half 0 (mt 0..3) + load B s=0 ----
#pragma unroll
    for (int nt = 0; nt < 4; ++nt)
      bf0[nt] = *(const bf16x8*)(bs + ((wn * 4 + nt) * 2 + 0) * 512 + lane * 8);
#pragma unroll
    for (int mt = 0; mt < 4; ++mt)
      af[mt] = *(const bf16x8*)(as + ((wm * 8 + mt) * 2 + 0) * 512 + lane * 8);
    __builtin_amdgcn_s_setprio(1);
#pragma unroll
    for (int mt = 0; mt < 4; ++mt)
#pragma unroll
      for (int nt = 0; nt < 4; ++nt)
        acc[mt][nt] = MFMA16(af[mt], bf0[nt], acc[mt][nt]);
    __builtin_amdgcn_s_setprio(0);

    // ---- phase 1: s=0, row-half 1 (mt 4..7), reuse bf0 ----
#pragma unroll
    for (int mt = 0; mt < 4; ++mt)
      af[mt] = *(const bf16x8*)(as + ((wm * 8 + 4 + mt) * 2 + 0) * 512 + lane * 8);
    __builtin_amdgcn_s_setprio(1);
#pragma unroll
    for (int mt = 0; mt < 4; ++mt)
#pragma unroll
      for (int nt = 0; nt < 4; ++nt)
        acc[4 + mt][nt] = MFMA16(af[mt], bf0[nt], acc[4 + mt][nt]);
    __builtin_amdgcn_s_setprio(0);

    // ---- phase 2: s=1, row-half 0 + load B s=1 ----
#pragma unroll
    for (int nt = 0; nt < 4; ++nt)
      bf1[nt] = *(const bf16x8*)(bs + ((wn * 4 + nt) * 2 + 1) * 512 + lane * 8);
#pragma unroll
    for (int mt = 0; mt < 4; ++mt)
      af[mt] = *(const bf16x8*)(as + ((wm * 8 + mt) * 2 + 1) * 512 + lane * 8);
    __builtin_amdgcn_s_setprio(1);
#pragma unroll
    for (int mt = 0; mt < 4; ++mt)
#pragma unroll
      for (int nt = 0; nt < 4; ++nt)
        acc[mt][nt] = MFMA16(af[mt], bf1[nt], acc[mt][nt]);
    __builtin_amdgcn_s_setprio(0);

    // ---- phase 3: s=1, row-half 1, reuse bf1 ----
#pragma unroll
    for (int mt = 0; mt < 4; ++mt)
      af[mt] = *(const bf16x8*)(as + ((wm * 8 + 4 + mt) * 2 + 1) * 512 + lane * 8);
    __builtin_amdgcn_s_setprio(1);
#pragma unroll
    for (int mt = 0; mt < 4; ++mt)
#pragma unroll
      for (int nt = 0; nt < 4; ++nt)
        acc[4 + mt][nt] = MFMA16(af[mt], bf1[nt], acc[4 + mt][nt]);
    __builtin_amdgcn_s_setprio(0);

    __builtin_amdgcn_s_barrier();   // all reads of buf[cur] done -> reusable
    cur ^= 1;
  }
#undef STAGE256

  // epilogue: C/D layout col = lane&15, row = quad*4 + e   [HW-verified m89]
  if (OUTM == 0) {
    bf16* Cb = (range == 0) ? Qb : (range == 1) ? Kb : Vb;
    const int ld = (range == 0) ? 2048 : 512;
    const int nb = (range == 0) ? n0 : (range == 1) ? n0 - 2048 : n0 - 2560;
#pragma unroll
    for (int mt = 0; mt < 8; ++mt) {
      int row = m0 + wm * 128 + mt * 16 + quad * 4;
#pragma unroll
      for (int nt = 0; nt < 4; ++nt) {
        int col = nb + wn * 64 + nt * 16 + lr;
#pragma unroll
        for (int e = 0; e < 4; ++e)
          Cb[(size_t)(row + e) * ld + col] = (bf16)acc[mt][nt][e];
      }
    }
  } else {
    float* Pb = (blockIdx.z == 0) ? P0 : P1;
#pragma unroll
    for (int mt = 0; mt < 8; ++mt) {
      int row = m0 + wm * 128 + mt * 16 + quad * 4;
#pragma unroll
      for (int nt = 0; nt < 4; ++nt) {
        int col = n0 + wn * 64 + nt * 16 + lr;
#pragma unroll
        for (int e = 0; e < 4; ++e)
          Pb[(size_t)(row + e) * 2048 + col] = acc[mt][nt][e];
      }
    }
  }
}

// ---------------------------------------------------------------------------
// RoPE + clip (+scale fold), in place, vectorized: 8 (j,j+64) pairs/thread.
// ---------------------------------------------------------------------------
__global__ void rope_clip(bf16* __restrict__ X, int heads, float scl) {
  int tpr = heads * 8;
  int idx = blockIdx.x * 256 + threadIdx.x;
  if (idx >= 4096 * tpr) return;
  int r = idx / tpr;
  int rem = idx - r * tpr;
  int h = rem >> 3, j0 = (rem & 7) * 8;
  int l = r & 2047;
  size_t base = (size_t)r * (heads * 128) + h * 128 + j0;
  bf16x8 x1 = *(const bf16x8*)(X + base);
  bf16x8 x2 = *(const bf16x8*)(X + base + 64);
  bf16x8 y1, y2;
#pragma unroll
  for (int t = 0; t < 8; ++t) {
    int j = j0 + t;
    float inv = expf(-(float)j * (9.210340371976184f / 64.0f));
    float s, c;
    sincosf((float)l * inv, &s, &c);
    float a = (float)x1[t], b = (float)x2[t];
    float u = a * c - b * s;
    float v = a * s + b * c;
    y1[t] = (bf16)(fminf(fmaxf(u, -50.f), 50.f) * scl);
    y2[t] = (bf16)(fminf(fmaxf(v, -50.f), 50.f) * scl);
  }
  *(bf16x8*)(X + base)      = y1;
  *(bf16x8*)(X + base + 64) = y2;
}

// ---------------------------------------------------------------------------
// Transpose per batch: in (R x Cc) -> out (Cc x R).
// ---------------------------------------------------------------------------
__global__ void transpose_bf16(const bf16* __restrict__ in, bf16* __restrict__ out,
                               int R, int Cc) {
  __shared__ bf16 t[32][33];
  int b = blockIdx.z;
  const bf16* ip = in + (size_t)b * R * Cc;
  bf16* op = out + (size_t)b * R * Cc;
  int c0 = blockIdx.x * 32, r0 = blockIdx.y * 32;
  int lx = threadIdx.x, ly = threadIdx.y;
#pragma unroll
  for (int i = 0; i < 32; i += 8)
    t[ly + i][lx] = ip[(size_t)(r0 + ly + i) * Cc + c0 + lx];
  __syncthreads();
#pragma unroll
  for (int i = 0; i < 32; i += 8)
    op[(size_t)(c0 + ly + i) * R + r0 + lx] = t[lx][ly + i];
}

// ---------------------------------------------------------------------------
// Flash v6 (unchanged, verified): causal GQA, uniform-work paired blocks +
// 2-phase counted-vmcnt pipeline. 256 blocks = 1/CU, balanced.
// ---------------------------------------------------------------------------
__global__ __launch_bounds__(512, 2) void flash(const bf16* __restrict__ Q,
                                                const bf16* __restrict__ Kp,
                                                const bf16* __restrict__ Vt,
                                                bf16* __restrict__ Ctx) {
  __shared__ alignas(16) bf16 Ks[2][16 * 512];   // 2 x 16 KB
  __shared__ alignas(16) bf16 Vs[2][16 * 512];   // 2 x 16 KB
  __shared__ alignas(16) bf16 Ps[8][32 * 72];    // 36 KB

  const int tid  = threadIdx.x;
  const int wave = tid >> 6, lane = tid & 63;
  const int lr = lane & 15, quad = lane >> 4;
  const int bh = blockIdx.y;
  const int b = bh >> 4, h = bh & 15, hk = h >> 2;
  const int p = blockIdx.x;                     // 0..7 -> pair (p, 15-p)
  const int qA0 = p * 128, qB0 = (15 - p) * 128;
  const int qbA = qA0 + wave * 16;              // wave's rows in tile A
  const int qbB = qB0 + wave * 16;              // wave's rows in tile B
  const int nt = (qB0 + 128) >> 6;              // 32 - 2p chunk iterations

  // Q fragments for both tiles
  bf16x8 qfA[4], qfB[4];
  {
    const bf16* qa = Q + ((size_t)(b * 2048 + qbA + lr)) * 2048 + h * 128 + quad * 8;
    const bf16* qbp = Q + ((size_t)(b * 2048 + qbB + lr)) * 2048 + h * 128 + quad * 8;
#pragma unroll
    for (int ks = 0; ks < 4; ++ks) {
      qfA[ks] = *(const bf16x8*)(qa + ks * 32);
      qfB[ks] = *(const bf16x8*)(qbp + ks * 32);
    }
  }

  f32x4 vzero = {0.f, 0.f, 0.f, 0.f};
  f32x4 oA[8], oB[8];
#pragma unroll
  for (int dt = 0; dt < 8; ++dt) { oA[dt] = vzero; oB[dt] = vzero; }
  float flsA[4] = {0.f, 0.f, 0.f, 0.f};
  float flsB[4] = {0.f, 0.f, 0.f, 0.f};

  const bf16* kbase = Kp + (size_t)(b * 2048) * 512 + hk * 128;
  const bf16* vbase = Vt + ((size_t)(b * 512 + hk * 128)) * 2048;

  // stage 32 frag-chunks (16 K + 16 V), 4 per wave, fragment-ordered
#define STAGE(bufi, kk)                                                         \
  do {                                                                          \
    _Pragma("unroll") for (int j = 0; j < 4; ++j) {                             \
      int c = wave * 4 + j;                                                     \
      if (c < 16) {                                                             \
        gl_lds16(kbase + (size_t)((kk) + (c >> 2) * 16 + lr) * 512 +            \
                     (c & 3) * 32 + quad * 8,                                   \
                 &Ks[bufi][c * 512]);                                           \
      } else {                                                                  \
        int c2 = c - 16;                                                        \
        gl_lds16(vbase + (size_t)((c2 >> 1) * 16 + lr) * 2048 + (kk) +          \
                     (c2 & 1) * 32 + quad * 8,                                  \
                 &Vs[bufi][c2 * 512]);                                          \
      }                                                                         \
    }                                                                           \
  } while (0)

  STAGE(0, 0);  // prologue: chunk 0 -> buf 0
  int cur = 0;

  for (int t = 0; t < nt; ++t) {
    const int k0 = t * 64;
    if (t + 1 < nt) {
      STAGE(cur ^ 1, k0 + 64);  // issue next chunk before compute
      asm volatile("s_waitcnt vmcnt(4)" ::: "memory");  // wait prev chunk only
    } else {
      asm volatile("s_waitcnt vmcnt(0)" ::: "memory");
    }
    __builtin_amdgcn_s_barrier();   // all waves: chunk t fully staged

    const bf16* ksb = Ks[cur];
    const bf16* vsb = Vs[cur];

    if (k0 <= qbA + 15) {
      // ---- dual: tile A active => tile B active (and B never masked here) --
      f32x4 sA[4], sB[4];
#pragma unroll
      for (int kt = 0; kt < 4; ++kt) { sA[kt] = vzero; sB[kt] = vzero; }
#pragma unroll
      for (int ks = 0; ks < 4; ++ks) {
#pragma unroll
        for (int kt = 0; kt < 4; ++kt) {
          bf16x8 kf = *(const bf16x8*)(ksb + (kt * 4 + ks) * 512 + lane * 8);
          sA[kt] = MFMA16(qfA[ks], kf, sA[kt]);
          sB[kt] = MFMA16(qfB[ks], kf, sB[kt]);
        }
      }
      bf16* pwA = Ps[wave];
      bf16* pwB = Ps[wave] + 16 * 72;
#pragma unroll
      for (int kt = 0; kt < 4; ++kt) {
        int kid = k0 + kt * 16 + lr;
#pragma unroll
        for (int e = 0; e < 4; ++e) {
          int qr = quad * 4 + e;
          float pa = (kid <= qbA + qr) ? __expf(sA[kt][e]) : 0.f;
          float pb = __expf(sB[kt][e]);  // kid < 1024 <= qbB always
          flsA[e] += pa;
          flsB[e] += pb;
          pwA[qr * 72 + kt * 16 + lr] = (bf16)pa;
          pwB[qr * 72 + kt * 16 + lr] = (bf16)pb;
        }
      }
#pragma unroll
      for (int ks2 = 0; ks2 < 2; ++ks2) {
        bf16x8 pfA = *(const bf16x8*)(pwA + (size_t)lr * 72 + ks2 * 32 + quad * 8);
        bf16x8 pfB = *(const bf16x8*)(pwB + (size_t)lr * 72 + ks2 * 32 + quad * 8);
#pragma unroll
        for (int dt = 0; dt < 8; ++dt) {
          bf16x8 vf = *(const bf16x8*)(vsb + (dt * 2 + ks2) * 512 + lane * 8);
          oA[dt] = MFMA16(pfA, vf, oA[dt]);
          oB[dt] = MFMA16(pfB, vf, oB[dt]);
        }
      }
    } else if (k0 <= qbB + 15) {
      // ---- tile B only ----
      f32x4 s[4];
#pragma unroll
      for (int kt = 0; kt < 4; ++kt) s[kt] = vzero;
#pragma unroll
      for (int ks = 0; ks < 4; ++ks) {
#pragma unroll
        for (int kt = 0; kt < 4; ++kt) {
          bf16x8 kf = *(const bf16x8*)(ksb + (kt * 4 + ks) * 512 + lane * 8);
          s[kt] = MFMA16(qfB[ks], kf, s[kt]);
        }
      }
      bf16* pwB = Ps[wave] + 16 * 72;
#pragma unroll
      for (int kt = 0; kt < 4; ++kt) {
        int kid = k0 + kt * 16 + lr;
#pragma unroll
        for (int e = 0; e < 4; ++e) {
          int qr = quad * 4 + e;
          float pb = (kid <= qbB + qr) ? __expf(s[kt][e]) : 0.f;
          flsB[e] += pb;
          pwB[qr * 72 + kt * 16 + lr] = (bf16)pb;
        }
      }
#pragma unroll
      for (int ks2 = 0; ks2 < 2; ++ks2) {
        bf16x8 pf = *(const bf16x8*)(pwB + (size_t)lr * 72 + ks2 * 32 + quad * 8);
#pragma unroll
        for (int dt = 0; dt < 8; ++dt) {
          bf16x8 vf = *(const bf16x8*)(vsb + (dt * 2 + ks2) * 512 + lane * 8);
          oB[dt] = MFMA16(pf, vf, oB[dt]);
        }
      }
    }
    __builtin_amdgcn_s_barrier();   // all reads of buf[cur] done -> reusable
    cur ^= 1;
  }
#undef STAGE

  // denominator reduce across the 16 key-lanes
#pragma unroll
  for (int e = 0; e < 4; ++e) {
    float sa = flsA[e];
    sa += __shfl_xor(sa, 1);
    sa += __shfl_xor(sa, 2);
    sa += __shfl_xor(sa, 4);
    sa += __shfl_xor(sa, 8);
    flsA[e] = 1.0f / sa;
    float sb = flsB[e];
    sb += __shfl_xor(sb, 1);
    sb += __shfl_xor(sb, 2);
    sb += __shfl_xor(sb, 4);
    sb += __shfl_xor(sb, 8);
    flsB[e] = 1.0f / sb;
  }

  bf16* ca = Ctx + ((size_t)(b * 2048 + qbA + quad * 4)) * 2048 + h * 128 + lr;
  bf16* cb = Ctx + ((size_t)(b * 2048 + qbB + quad * 4)) * 2048 + h * 128 + lr;
#pragma unroll
  for (int dt = 0; dt < 8; ++dt)
#pragma unroll
    for (int e = 0; e < 4; ++e) {
      ca[(size_t)e * 2048 + dt * 16] = (bf16)(oA[dt][e] * flsA[e]);
      cb[(size_t)e * 2048 + dt * 16] = (bf16)(oB[dt][e] * flsB[e]);
    }
}

// ---------------------------------------------------------------------------
extern "C" void kernel_launch(void* const* d_in, const int* in_sizes, int n_in,
                              void* d_out, int out_size, void* d_ws, size_t ws_size,
                              hipStream_t stream) {
  (void)in_sizes; (void)n_in; (void)out_size; (void)ws_size;
  const float* query = (const float*)d_in[0];
  const float* key_t = (const float*)d_in[1];
  const float* value = (const float*)d_in[2];
  // d_in[3] = mask (causal tril) — applied analytically
  const float* Wq = (const float*)d_in[4];
  const float* Wk = (const float*)d_in[5];
  const float* Wv = (const float*)d_in[6];
  const float* Wo = (const float*)d_in[7];

  const size_t MB = 1024ull * 1024ull;
  char* ws  = (char*)d_ws;
  bf16* qbf = (bf16*)(ws);                  // [0,16)  query bf16
  bf16* wqb = (bf16*)(ws + 16 * MB);        // [16,24)  Wq bf16   (contiguous
  bf16* wkb = (bf16*)(ws + 24 * MB);        // [24,26)  Wk bf16    3072x2048
  bf16* wvb = (bf16*)(ws + 26 * MB);        // [26,28)  Wv bf16    W block)
  bf16* wob = (bf16*)(ws + 28 * MB);        // [28,36)
  bf16* Qb  = (bf16*)(ws + 36 * MB);        // [36,52)
  bf16* Kb  = (bf16*)(ws + 52 * MB);        // [52,56)
  bf16* Vb  = (bf16*)(ws + 56 * MB);        // [56,60)
  bf16* Vtb = (bf16*)(ws + 60 * MB);        // [60,64)
  bf16* kb16 = (bf16*)(ws + 64 * MB);       // [64,80)  key_t bf16
  bf16* vb16 = (bf16*)(ws + 80 * MB);       // [80,96)  value bf16
  bf16* Ctx = qbf;                          // alias: qbf dead after QKV-proj
  float* p1 = (float*)(ws + 36 * MB);       // [36,68) O-proj K-half-1 partial
                                            // (over Qb..Vtb+kb16 head: all dead
                                            //  by the time O-proj runs)

  cvt_f32_bf16<<<4096, 256, 0, stream>>>(query, qbf, 1048576);
  cvt_f32_bf16<<<4096, 256, 0, stream>>>(key_t, kb16, 1048576);
  cvt_f32_bf16<<<4096, 256, 0, stream>>>(value, vb16, 1048576);
  cvt_f32_bf16<<<2048, 256, 0, stream>>>(Wq, wqb, 524288);
  cvt_f32_bf16<<<512, 256, 0, stream>>>(Wk, wkb, 131072);
  cvt_f32_bf16<<<512, 256, 0, stream>>>(Wv, wvb, 131072);
  cvt_f32_bf16<<<2048, 256, 0, stream>>>(Wo, wob, 524288);

  // FUSED Q+K+V projection: 256^2 verified schedule, N=3072, 192 blocks
  gemm256<0><<<dim3(12, 16), 512, 0, stream>>>(qbf, kb16, vb16, wqb,
                                               Qb, Kb, Vb, nullptr, nullptr);

  rope_clip<<<2048, 256, 0, stream>>>(Qb, 16, 0.08838834764831845f);
  rope_clip<<<512, 256, 0, stream>>>(Kb, 4, 1.0f);

  transpose_bf16<<<dim3(16, 64, 2), dim3(32, 8), 0, stream>>>(Vb, Vtb, 2048, 512);

  flash<<<dim3(8, 32), 512, 0, stream>>>(Qb, Kb, Vtb, Ctx);

  // O-projection: 256^2 verified schedule, split-K=2 -> 256 blocks (full
  // fill); z=0 partial straight to d_out (f32), z=1 to p1; then fold.
  gemm256<1><<<dim3(8, 16, 2), 512, 0, stream>>>(Ctx, nullptr, nullptr, wob,
                                                 nullptr, nullptr, nullptr,
                                                 (float*)d_out, p1);
  add_f32<<<8192, 256, 0, stream>>>((float*)d_out, p1, 2097152);
}

// Round 11
// 419.644 us; speedup vs baseline: 1.0404x; 1.0404x over previous
//
#include <hip/hip_runtime.h>

typedef __bf16 bf16;
typedef __bf16 bf16x8 __attribute__((ext_vector_type(8)));
typedef float  f32x4  __attribute__((ext_vector_type(4)));

#define MFMA16(a, b, c) __builtin_amdgcn_mfma_f32_16x16x32_bf16((a), (b), (c), 0, 0, 0)

// async global->LDS, 16 B per lane: lane l -> ldsbase + l*16 (wave-uniform base).
__device__ inline void gl_lds16(const bf16* g, bf16* l) {
  __builtin_amdgcn_global_load_lds(
      (const __attribute__((address_space(1))) void*)g,
      (__attribute__((address_space(3))) void*)l, 16, 0, 0);
}

__device__ inline bf16x8 cvt8(const float* __restrict__ f) {
  float4 a = *(const float4*)f;
  float4 b = *(const float4*)(f + 4);
  bf16x8 r;
  r[0] = (bf16)a.x; r[1] = (bf16)a.y; r[2] = (bf16)a.z; r[3] = (bf16)a.w;
  r[4] = (bf16)b.x; r[5] = (bf16)b.y; r[6] = (bf16)b.z; r[7] = (bf16)b.w;
  return r;
}

// ---------------------------------------------------------------------------
// Fused input conversion: query|key_t|value f32 -> bf16 in one launch.
// 3 x 4096 block ranges, each exactly covering 1048576 8-elt units.
// ---------------------------------------------------------------------------
__global__ void cvt_inputs(const float* __restrict__ q, const float* __restrict__ k,
                           const float* __restrict__ v, bf16* __restrict__ qd,
                           bf16* __restrict__ kd, bf16* __restrict__ vd) {
  int bid = blockIdx.x;
  const float* s;
  bf16* d;
  int off;
  if (bid < 4096)      { s = q; d = qd; off = bid; }
  else if (bid < 8192) { s = k; d = kd; off = bid - 4096; }
  else                 { s = v; d = vd; off = bid - 8192; }
  size_t i = (size_t)off * 256 + threadIdx.x;
  *(bf16x8*)(d + i * 8) = cvt8(s + i * 8);
}

// ---------------------------------------------------------------------------
// Fused weight conversion: Wq|Wk|Wv|Wo -> contiguous bf16 block at dst
// (wqb|wkb|wvb|wob laid back-to-back in workspace). 5120 blocks:
// [0,2048)=Wq, [2048,2560)=Wk, [2560,3072)=Wv, [3072,5120)=Wo.
// ---------------------------------------------------------------------------
__global__ void cvt_weights(const float* __restrict__ wq, const float* __restrict__ wk,
                            const float* __restrict__ wv, const float* __restrict__ wo,
                            bf16* __restrict__ dst) {
  int bid = blockIdx.x;
  const float* s;
  int off;
  if (bid < 2048)      { s = wq; off = bid; }
  else if (bid < 2560) { s = wk; off = bid - 2048; }
  else if (bid < 3072) { s = wv; off = bid - 2560; }
  else                 { s = wo; off = bid - 3072; }
  size_t u = (size_t)off * 256 + threadIdx.x;          // unit within source
  size_t g = (size_t)bid * 256 + threadIdx.x;          // unit within dst block
  *(bf16x8*)(dst + g * 8) = cvt8(s + u * 8);
}

// ---------------------------------------------------------------------------
// FUSED QKV projection, 256x256 TILE — the ROUND-6-VERIFIED schedule
// (measured 100 us, MfmaUtil 20%, FETCH 110 MB, 0 bank conflicts).
// NOTE: the deep half-tile pipeline variant (3 halves in flight, vmcnt
// never 0) hung the bench container in 3/3 attempts (r7/r8/r10) and is
// abandoned; the 687 TF/CU 2-phase plateau is this structure's ceiling.
// 8 waves (2M x 4N), BK=64, dbuf, counted vmcnt(8), 4 setprio phases.
// N = 3072 = 2048(Q)+512(K)+512(V); W = contiguous wqb|wkb|wvb rows.
// LDS 128 KB -> 1 block/CU, 2 waves/SIMD.
// ---------------------------------------------------------------------------
__global__ __launch_bounds__(512, 2) void gemm_qkv256(const bf16* __restrict__ qA,
                                                      const bf16* __restrict__ kA,
                                                      const bf16* __restrict__ vA,
                                                      const bf16* __restrict__ W,
                                                      bf16* __restrict__ Qb,
                                                      bf16* __restrict__ Kb,
                                                      bf16* __restrict__ Vb) {
  __shared__ alignas(16) bf16 As[2][32 * 512];   // 2 x 32 KB, frag-ordered
  __shared__ alignas(16) bf16 Bs[2][32 * 512];   // 2 x 32 KB

  const int tid  = threadIdx.x;
  const int wave = tid >> 6, lane = tid & 63;
  const int wm = wave >> 2, wn = wave & 3;       // 2M x 4N wave grid
  const int lr = lane & 15, quad = lane >> 4;
  const int n0 = blockIdx.x * 256, m0 = blockIdx.y * 256;
  const int NS = 32;                             // K/BK = 2048/64

  const int range = (n0 < 2048) ? 0 : (n0 < 2560) ? 1 : 2;
  const bf16* Ab = (range == 0) ? qA : (range == 1) ? kA : vA;

  f32x4 vzero = {0.f, 0.f, 0.f, 0.f};
  f32x4 acc[8][4];
#pragma unroll
  for (int mt = 0; mt < 8; ++mt)
#pragma unroll
    for (int nt = 0; nt < 4; ++nt) acc[mt][nt] = vzero;

  // stage 64 frag-chunks (32 A + 32 B), 8 per wave.  Chunk c: row-block
  // mi=c>>1, k-slice s=c&1; lane l holds rows mi*16+(l&15),
  // cols k0+s*32+(l>>4)*8..+7  -> LDS linear at chunk*1KB + lane*16B.
#define STAGE256(bufi, kk)                                                      \
  do {                                                                          \
    _Pragma("unroll") for (int j = 0; j < 4; ++j) {                             \
      int c = wave * 4 + j;                                                     \
      int mi = c >> 1, sl = c & 1;                                              \
      gl_lds16(Ab + (size_t)(m0 + mi * 16 + lr) * 2048 + (kk) + sl * 32 + quad * 8, \
               &As[bufi][c * 512]);                                             \
      gl_lds16(W + (size_t)(n0 + mi * 16 + lr) * 2048 + (kk) + sl * 32 + quad * 8,  \
               &Bs[bufi][c * 512]);                                             \
    }                                                                           \
  } while (0)

  STAGE256(0, 0);
  int cur = 0;
  for (int t = 0; t < NS; ++t) {
    if (t + 1 < NS) {
      STAGE256(cur ^ 1, (t + 1) * 64);
      asm volatile("s_waitcnt vmcnt(8)" ::: "memory");  // tile t complete
    } else {
      asm volatile("s_waitcnt vmcnt(0)" ::: "memory");
    }
    __builtin_amdgcn_s_barrier();

    const bf16* as = As[cur];
    const bf16* bs = Bs[cur];
    bf16x8 af[4], bf0[4], bf1[4];

    // ---- phase 0: s=0, row-half 0 (mt 0..3) + load B s=0 ----
#pragma unroll
    for (int nt = 0; nt < 4; ++nt)
      bf0[nt] = *(const bf16x8*)(bs + ((wn * 4 + nt) * 2 + 0) * 512 + lane * 8);
#pragma unroll
    for (int mt = 0; mt < 4; ++mt)
      af[mt] = *(const bf16x8*)(as + ((wm * 8 + mt) * 2 + 0) * 512 + lane * 8);
    __builtin_amdgcn_s_setprio(1);
#pragma unroll
    for (int mt = 0; mt < 4; ++mt)
#pragma unroll
      for (int nt = 0; nt < 4; ++nt)
        acc[mt][nt] = MFMA16(af[mt], bf0[nt], acc[mt][nt]);
    __builtin_amdgcn_s_setprio(0);

    // ---- phase 1: s=0, row-half 1 (mt 4..7), reuse bf0 ----
#pragma unroll
    for (int mt = 0; mt < 4; ++mt)
      af[mt] = *(const bf16x8*)(as + ((wm * 8 + 4 + mt) * 2 + 0) * 512 + lane * 8);
    __builtin_amdgcn_s_setprio(1);
#pragma unroll
    for (int mt = 0; mt < 4; ++mt)
#pragma unroll
      for (int nt = 0; nt < 4; ++nt)
        acc[4 + mt][nt] = MFMA16(af[mt], bf0[nt], acc[4 + mt][nt]);
    __builtin_amdgcn_s_setprio(0);

    // ---- phase 2: s=1, row-half 0 + load B s=1 ----
#pragma unroll
    for (int nt = 0; nt < 4; ++nt)
      bf1[nt] = *(const bf16x8*)(bs + ((wn * 4 + nt) * 2 + 1) * 512 + lane * 8);
#pragma unroll
    for (int mt = 0; mt < 4; ++mt)
      af[mt] = *(const bf16x8*)(as + ((wm * 8 + mt) * 2 + 1) * 512 + lane * 8);
    __builtin_amdgcn_s_setprio(1);
#pragma unroll
    for (int mt = 0; mt < 4; ++mt)
#pragma unroll
      for (int nt = 0; nt < 4; ++nt)
        acc[mt][nt] = MFMA16(af[mt], bf1[nt], acc[mt][nt]);
    __builtin_amdgcn_s_setprio(0);

    // ---- phase 3: s=1, row-half 1, reuse bf1 ----
#pragma unroll
    for (int mt = 0; mt < 4; ++mt)
      af[mt] = *(const bf16x8*)(as + ((wm * 8 + 4 + mt) * 2 + 1) * 512 + lane * 8);
    __builtin_amdgcn_s_setprio(1);
#pragma unroll
    for (int mt = 0; mt < 4; ++mt)
#pragma unroll
      for (int nt = 0; nt < 4; ++nt)
        acc[4 + mt][nt] = MFMA16(af[mt], bf1[nt], acc[4 + mt][nt]);
    __builtin_amdgcn_s_setprio(0);

    __builtin_amdgcn_s_barrier();   // all reads of buf[cur] done -> reusable
    cur ^= 1;
  }
#undef STAGE256

  // epilogue: C/D layout col = lane&15, row = quad*4 + e   [HW-verified m89]
  bf16* Cb = (range == 0) ? Qb : (range == 1) ? Kb : Vb;
  const int ld = (range == 0) ? 2048 : 512;
  const int nb = (range == 0) ? n0 : (range == 1) ? n0 - 2048 : n0 - 2560;
#pragma unroll
  for (int mt = 0; mt < 8; ++mt) {
    int row = m0 + wm * 128 + mt * 16 + quad * 4;
#pragma unroll
    for (int nt = 0; nt < 4; ++nt) {
      int col = nb + wn * 64 + nt * 16 + lr;
#pragma unroll
      for (int e = 0; e < 4; ++e)
        Cb[(size_t)(row + e) * ld + col] = (bf16)acc[mt][nt][e];
    }
  }
}

// ---------------------------------------------------------------------------
// O-projection GEMM (round-6-verified): 128x128, 2-phase counted-vmcnt dbuf,
// 512 blocks = 2/CU. C = A @ W^T, bf16 in, f32 out.
// (split-K=2 variant measured net-negative in r9: add_f32 cost > gain.)
// ---------------------------------------------------------------------------
template <bool OUTF32>
__global__ __launch_bounds__(256) void gemm_bt(const bf16* __restrict__ Ap,
                                               const bf16* __restrict__ W,
                                               void* __restrict__ C0,
                                               int ld0, int M, int N, int K) {
  __shared__ alignas(16) bf16 As[2][16 * 512];
  __shared__ alignas(16) bf16 Bs[2][16 * 512];

  const int tid  = threadIdx.x;
  const int wave = tid >> 6, lane = tid & 63;
  const int wm = wave >> 1, wn = wave & 1;
  const int lr = lane & 15, quad = lane >> 4;
  const int m0 = blockIdx.y * 128, n0 = blockIdx.x * 128;
  const int NS = K >> 6;

  f32x4 vzero = {0.f, 0.f, 0.f, 0.f};
  f32x4 acc[4][4];
#pragma unroll
  for (int mt = 0; mt < 4; ++mt)
#pragma unroll
    for (int nt = 0; nt < 4; ++nt) acc[mt][nt] = vzero;

#define STAGE8(bufi, kk)                                                        \
  do {                                                                          \
    _Pragma("unroll") for (int j = 0; j < 4; ++j) {                             \
      int c = wave * 4 + j;                                                     \
      gl_lds16(W + (size_t)(n0 + (c >> 1) * 16 + lr) * K + (kk) +               \
                   (c & 1) * 32 + quad * 8,                                     \
               &Bs[bufi][c * 512]);                                             \
      gl_lds16(Ap + (size_t)(m0 + (c >> 1) * 16 + lr) * K + (kk) +              \
                   (c & 1) * 32 + quad * 8,                                     \
               &As[bufi][c * 512]);                                             \
    }                                                                           \
  } while (0)

  STAGE8(0, 0);
  int cur = 0;
  for (int t = 0; t < NS; ++t) {
    if (t + 1 < NS) {
      STAGE8(cur ^ 1, (t + 1) * 64);
      asm volatile("s_waitcnt vmcnt(8)" ::: "memory");
    } else {
      asm volatile("s_waitcnt vmcnt(0)" ::: "memory");
    }
    __builtin_amdgcn_s_barrier();
#pragma unroll
    for (int s = 0; s < 2; ++s) {
      bf16x8 af[4], bfg[4];
#pragma unroll
      for (int mt = 0; mt < 4; ++mt)
        af[mt] = *(const bf16x8*)(&As[cur][((wm * 4 + mt) * 2 + s) * 512] + lane * 8);
#pragma unroll
      for (int nt = 0; nt < 4; ++nt)
        bfg[nt] = *(const bf16x8*)(&Bs[cur][((wn * 4 + nt) * 2 + s) * 512] + lane * 8);
      __builtin_amdgcn_s_setprio(1);
#pragma unroll
      for (int mt = 0; mt < 4; ++mt)
#pragma unroll
        for (int nt = 0; nt < 4; ++nt)
          acc[mt][nt] = MFMA16(af[mt], bfg[nt], acc[mt][nt]);
      __builtin_amdgcn_s_setprio(0);
    }
    __builtin_amdgcn_s_barrier();
    cur ^= 1;
  }
#undef STAGE8

  // epilogue: C/D layout col = lane&15, row = quad*4 + e   [HW-verified m89]
#pragma unroll
  for (int mt = 0; mt < 4; ++mt) {
    int row = m0 + wm * 64 + mt * 16 + quad * 4;
#pragma unroll
    for (int nt = 0; nt < 4; ++nt) {
      int col = n0 + wn * 64 + nt * 16 + lr;
#pragma unroll
      for (int e = 0; e < 4; ++e) {
        if (OUTF32)
          ((float*)C0)[(size_t)(row + e) * ld0 + col] = acc[mt][nt][e];
        else
          ((bf16*)C0)[(size_t)(row + e) * ld0 + col] = (bf16)acc[mt][nt][e];
      }
    }
  }
}

// ---------------------------------------------------------------------------
// RoPE + clip (+scale fold), Q and K fused into one launch.
// blocks [0,2048) -> Q (16 heads, scale folded); [2048,2560) -> K (4 heads).
// ---------------------------------------------------------------------------
__device__ inline void rope_body(bf16* __restrict__ X, int heads, float scl,
                                 int idx) {
  int tpr = heads * 8;
  int r = idx / tpr;
  int rem = idx - r * tpr;
  int h = rem >> 3, j0 = (rem & 7) * 8;
  int l = r & 2047;
  size_t base = (size_t)r * (heads * 128) + h * 128 + j0;
  bf16x8 x1 = *(const bf16x8*)(X + base);
  bf16x8 x2 = *(const bf16x8*)(X + base + 64);
  bf16x8 y1, y2;
#pragma unroll
  for (int t = 0; t < 8; ++t) {
    int j = j0 + t;
    float inv = expf(-(float)j * (9.210340371976184f / 64.0f));
    float s, c;
    sincosf((float)l * inv, &s, &c);
    float a = (float)x1[t], b = (float)x2[t];
    float u = a * c - b * s;
    float v = a * s + b * c;
    y1[t] = (bf16)(fminf(fmaxf(u, -50.f), 50.f) * scl);
    y2[t] = (bf16)(fminf(fmaxf(v, -50.f), 50.f) * scl);
  }
  *(bf16x8*)(X + base)      = y1;
  *(bf16x8*)(X + base + 64) = y2;
}

__global__ void rope_clip2(bf16* __restrict__ Qb, bf16* __restrict__ Kb) {
  int bid = blockIdx.x;
  if (bid < 2048)
    rope_body(Qb, 16, 0.08838834764831845f, bid * 256 + threadIdx.x);
  else
    rope_body(Kb, 4, 1.0f, (bid - 2048) * 256 + threadIdx.x);
}

// ---------------------------------------------------------------------------
// Transpose per batch: in (R x Cc) -> out (Cc x R).
// ---------------------------------------------------------------------------
__global__ void transpose_bf16(const bf16* __restrict__ in, bf16* __restrict__ out,
                               int R, int Cc) {
  __shared__ bf16 t[32][33];
  int b = blockIdx.z;
  const bf16* ip = in + (size_t)b * R * Cc;
  bf16* op = out + (size_t)b * R * Cc;
  int c0 = blockIdx.x * 32, r0 = blockIdx.y * 32;
  int lx = threadIdx.x, ly = threadIdx.y;
#pragma unroll
  for (int i = 0; i < 32; i += 8)
    t[ly + i][lx] = ip[(size_t)(r0 + ly + i) * Cc + c0 + lx];
  __syncthreads();
#pragma unroll
  for (int i = 0; i < 32; i += 8)
    op[(size_t)(c0 + ly + i) * R + r0 + lx] = t[lx][ly + i];
}

// ---------------------------------------------------------------------------
// Flash v6 (unchanged, verified): causal GQA, uniform-work paired blocks +
// 2-phase counted-vmcnt pipeline. 256 blocks = 1/CU, balanced.
// ---------------------------------------------------------------------------
__global__ __launch_bounds__(512, 2) void flash(const bf16* __restrict__ Q,
                                                const bf16* __restrict__ Kp,
                                                const bf16* __restrict__ Vt,
                                                bf16* __restrict__ Ctx) {
  __shared__ alignas(16) bf16 Ks[2][16 * 512];   // 2 x 16 KB
  __shared__ alignas(16) bf16 Vs[2][16 * 512];   // 2 x 16 KB
  __shared__ alignas(16) bf16 Ps[8][32 * 72];    // 36 KB

  const int tid  = threadIdx.x;
  const int wave = tid >> 6, lane = tid & 63;
  const int lr = lane & 15, quad = lane >> 4;
  const int bh = blockIdx.y;
  const int b = bh >> 4, h = bh & 15, hk = h >> 2;
  const int p = blockIdx.x;                     // 0..7 -> pair (p, 15-p)
  const int qA0 = p * 128, qB0 = (15 - p) * 128;
  const int qbA = qA0 + wave * 16;              // wave's rows in tile A
  const int qbB = qB0 + wave * 16;              // wave's rows in tile B
  const int nt = (qB0 + 128) >> 6;              // 32 - 2p chunk iterations

  // Q fragments for both tiles
  bf16x8 qfA[4], qfB[4];
  {
    const bf16* qa = Q + ((size_t)(b * 2048 + qbA + lr)) * 2048 + h * 128 + quad * 8;
    const bf16* qbp = Q + ((size_t)(b * 2048 + qbB + lr)) * 2048 + h * 128 + quad * 8;
#pragma unroll
    for (int ks = 0; ks < 4; ++ks) {
      qfA[ks] = *(const bf16x8*)(qa + ks * 32);
      qfB[ks] = *(const bf16x8*)(qbp + ks * 32);
    }
  }

  f32x4 vzero = {0.f, 0.f, 0.f, 0.f};
  f32x4 oA[8], oB[8];
#pragma unroll
  for (int dt = 0; dt < 8; ++dt) { oA[dt] = vzero; oB[dt] = vzero; }
  float flsA[4] = {0.f, 0.f, 0.f, 0.f};
  float flsB[4] = {0.f, 0.f, 0.f, 0.f};

  const bf16* kbase = Kp + (size_t)(b * 2048) * 512 + hk * 128;
  const bf16* vbase = Vt + ((size_t)(b * 512 + hk * 128)) * 2048;

  // stage 32 frag-chunks (16 K + 16 V), 4 per wave, fragment-ordered
#define STAGE(bufi, kk)                                                         \
  do {                                                                          \
    _Pragma("unroll") for (int j = 0; j < 4; ++j) {                             \
      int c = wave * 4 + j;                                                     \
      if (c < 16) {                                                             \
        gl_lds16(kbase + (size_t)((kk) + (c >> 2) * 16 + lr) * 512 +            \
                     (c & 3) * 32 + quad * 8,                                   \
                 &Ks[bufi][c * 512]);                                           \
      } else {                                                                  \
        int c2 = c - 16;                                                        \
        gl_lds16(vbase + (size_t)((c2 >> 1) * 16 + lr) * 2048 + (kk) +          \
                     (c2 & 1) * 32 + quad * 8,                                  \
                 &Vs[bufi][c2 * 512]);                                          \
      }                                                                         \
    }                                                                           \
  } while (0)

  STAGE(0, 0);  // prologue: chunk 0 -> buf 0
  int cur = 0;

  for (int t = 0; t < nt; ++t) {
    const int k0 = t * 64;
    if (t + 1 < nt) {
      STAGE(cur ^ 1, k0 + 64);  // issue next chunk before compute
      asm volatile("s_waitcnt vmcnt(4)" ::: "memory");  // wait prev chunk only
    } else {
      asm volatile("s_waitcnt vmcnt(0)" ::: "memory");
    }
    __builtin_amdgcn_s_barrier();   // all waves: chunk t fully staged

    const bf16* ksb = Ks[cur];
    const bf16* vsb = Vs[cur];

    if (k0 <= qbA + 15) {
      // ---- dual: tile A active => tile B active (and B never masked here) --
      f32x4 sA[4], sB[4];
#pragma unroll
      for (int kt = 0; kt < 4; ++kt) { sA[kt] = vzero; sB[kt] = vzero; }
#pragma unroll
      for (int ks = 0; ks < 4; ++ks) {
#pragma unroll
        for (int kt = 0; kt < 4; ++kt) {
          bf16x8 kf = *(const bf16x8*)(ksb + (kt * 4 + ks) * 512 + lane * 8);
          sA[kt] = MFMA16(qfA[ks], kf, sA[kt]);
          sB[kt] = MFMA16(qfB[ks], kf, sB[kt]);
        }
      }
      bf16* pwA = Ps[wave];
      bf16* pwB = Ps[wave] + 16 * 72;
#pragma unroll
      for (int kt = 0; kt < 4; ++kt) {
        int kid = k0 + kt * 16 + lr;
#pragma unroll
        for (int e = 0; e < 4; ++e) {
          int qr = quad * 4 + e;
          float pa = (kid <= qbA + qr) ? __expf(sA[kt][e]) : 0.f;
          float pb = __expf(sB[kt][e]);  // kid < 1024 <= qbB always
          flsA[e] += pa;
          flsB[e] += pb;
          pwA[qr * 72 + kt * 16 + lr] = (bf16)pa;
          pwB[qr * 72 + kt * 16 + lr] = (bf16)pb;
        }
      }
#pragma unroll
      for (int ks2 = 0; ks2 < 2; ++ks2) {
        bf16x8 pfA = *(const bf16x8*)(pwA + (size_t)lr * 72 + ks2 * 32 + quad * 8);
        bf16x8 pfB = *(const bf16x8*)(pwB + (size_t)lr * 72 + ks2 * 32 + quad * 8);
#pragma unroll
        for (int dt = 0; dt < 8; ++dt) {
          bf16x8 vf = *(const bf16x8*)(vsb + (dt * 2 + ks2) * 512 + lane * 8);
          oA[dt] = MFMA16(pfA, vf, oA[dt]);
          oB[dt] = MFMA16(pfB, vf, oB[dt]);
        }
      }
    } else if (k0 <= qbB + 15) {
      // ---- tile B only ----
      f32x4 s[4];
#pragma unroll
      for (int kt = 0; kt < 4; ++kt) s[kt] = vzero;
#pragma unroll
      for (int ks = 0; ks < 4; ++ks) {
#pragma unroll
        for (int kt = 0; kt < 4; ++kt) {
          bf16x8 kf = *(const bf16x8*)(ksb + (kt * 4 + ks) * 512 + lane * 8);
          s[kt] = MFMA16(qfB[ks], kf, s[kt]);
        }
      }
      bf16* pwB = Ps[wave] + 16 * 72;
#pragma unroll
      for (int kt = 0; kt < 4; ++kt) {
        int kid = k0 + kt * 16 + lr;
#pragma unroll
        for (int e = 0; e < 4; ++e) {
          int qr = quad * 4 + e;
          float pb = (kid <= qbB + qr) ? __expf(s[kt][e]) : 0.f;
          flsB[e] += pb;
          pwB[qr * 72 + kt * 16 + lr] = (bf16)pb;
        }
      }
#pragma unroll
      for (int ks2 = 0; ks2 < 2; ++ks2) {
        bf16x8 pf = *(const bf16x8*)(pwB + (size_t)lr * 72 + ks2 * 32 + quad * 8);
#pragma unroll
        for (int dt = 0; dt < 8; ++dt) {
          bf16x8 vf = *(const bf16x8*)(vsb + (dt * 2 + ks2) * 512 + lane * 8);
          oB[dt] = MFMA16(pf, vf, oB[dt]);
        }
      }
    }
    __builtin_amdgcn_s_barrier();   // all reads of buf[cur] done -> reusable
    cur ^= 1;
  }
#undef STAGE

  // denominator reduce across the 16 key-lanes
#pragma unroll
  for (int e = 0; e < 4; ++e) {
    float sa = flsA[e];
    sa += __shfl_xor(sa, 1);
    sa += __shfl_xor(sa, 2);
    sa += __shfl_xor(sa, 4);
    sa += __shfl_xor(sa, 8);
    flsA[e] = 1.0f / sa;
    float sb = flsB[e];
    sb += __shfl_xor(sb, 1);
    sb += __shfl_xor(sb, 2);
    sb += __shfl_xor(sb, 4);
    sb += __shfl_xor(sb, 8);
    flsB[e] = 1.0f / sb;
  }

  bf16* ca = Ctx + ((size_t)(b * 2048 + qbA + quad * 4)) * 2048 + h * 128 + lr;
  bf16* cb = Ctx + ((size_t)(b * 2048 + qbB + quad * 4)) * 2048 + h * 128 + lr;
#pragma unroll
  for (int dt = 0; dt < 8; ++dt)
#pragma unroll
    for (int e = 0; e < 4; ++e) {
      ca[(size_t)e * 2048 + dt * 16] = (bf16)(oA[dt][e] * flsA[e]);
      cb[(size_t)e * 2048 + dt * 16] = (bf16)(oB[dt][e] * flsB[e]);
    }
}

// ---------------------------------------------------------------------------
extern "C" void kernel_launch(void* const* d_in, const int* in_sizes, int n_in,
                              void* d_out, int out_size, void* d_ws, size_t ws_size,
                              hipStream_t stream) {
  (void)in_sizes; (void)n_in; (void)out_size; (void)ws_size;
  const float* query = (const float*)d_in[0];
  const float* key_t = (const float*)d_in[1];
  const float* value = (const float*)d_in[2];
  // d_in[3] = mask (causal tril) — applied analytically
  const float* Wq = (const float*)d_in[4];
  const float* Wk = (const float*)d_in[5];
  const float* Wv = (const float*)d_in[6];
  const float* Wo = (const float*)d_in[7];

  const size_t MB = 1024ull * 1024ull;
  char* ws  = (char*)d_ws;
  bf16* qbf = (bf16*)(ws);                  // [0,16)  query bf16
  bf16* wqb = (bf16*)(ws + 16 * MB);        // [16,24)  Wq bf16   (contiguous
  bf16* wob = (bf16*)(ws + 28 * MB);        // [28,36)   wqb|wkb|wvb|wob)
  bf16* Qb  = (bf16*)(ws + 36 * MB);        // [36,52)
  bf16* Kb  = (bf16*)(ws + 52 * MB);        // [52,56)
  bf16* Vb  = (bf16*)(ws + 56 * MB);        // [56,60)
  bf16* Vtb = (bf16*)(ws + 60 * MB);        // [60,64)
  bf16* kb16 = (bf16*)(ws + 64 * MB);       // [64,80)  key_t bf16
  bf16* vb16 = (bf16*)(ws + 80 * MB);       // [80,96)  value bf16
  bf16* Ctx = qbf;                          // alias: qbf dead after QKV-proj

  // 2 fused conversion launches (was 7)
  cvt_inputs<<<12288, 256, 0, stream>>>(query, key_t, value, qbf, kb16, vb16);
  cvt_weights<<<5120, 256, 0, stream>>>(Wq, Wk, Wv, Wo, wqb);

  // FUSED Q+K+V projection: 256^2 verified schedule, N=3072, 192 blocks
  gemm_qkv256<<<dim3(12, 16), 512, 0, stream>>>(qbf, kb16, vb16, wqb, Qb, Kb, Vb);

  // fused RoPE for Q (scale-folded) and K
  rope_clip2<<<2560, 256, 0, stream>>>(Qb, Kb);

  transpose_bf16<<<dim3(16, 64, 2), dim3(32, 8), 0, stream>>>(Vb, Vtb, 2048, 512);

  flash<<<dim3(8, 32), 512, 0, stream>>>(Qb, Kb, Vtb, Ctx);

  // O-projection: round-6-verified 128^2 2-phase, 512 blocks, f32 out
  gemm_bt<true><<<dim3(16, 32), 256, 0, stream>>>(
      Ctx, wob, (float*)d_out, 2048, 4096, 2048, 2048);
}